// Round 8
// baseline (7381.084 us; speedup 1.0000x reference)
//
#include <hip/hip_runtime.h>
#include <hip/hip_bf16.h>

#define BATCH 64
#define IN_SIZE 4096
#define IN_DIM 128
#define HEADS 2
#define OUT_SIZE 128
#define NPAIR (BATCH*HEADS)
#define NBLK (NPAIR*2)
#define INV_EPS 10.0f
#define MAX_ITER 50
#define A_MARG (1.0f/32.0f)

typedef unsigned int u32;
typedef __attribute__((ext_vector_type(8))) short bf16x8;
typedef __attribute__((ext_vector_type(4))) float f32x4;

__device__ __forceinline__ float bflo(u32 kk){ return __uint_as_float(kk<<16); }
__device__ __forceinline__ float bfhi(u32 kk){ return __uint_as_float(kk & 0xffff0000u); }
__device__ __forceinline__ unsigned short f2bf(float f){
    __hip_bfloat16 h = __float2bfloat16(f);
    return *(unsigned short*)&h;
}

template<int CTRL>
__device__ __forceinline__ float dpp_add(float x) {
    int yi = __builtin_amdgcn_update_dpp(0, __float_as_int(x), CTRL, 0xf, 0xf, false);
    return x + __int_as_float(yi);
}

// ---------------------------------------------------------------------------
// Kernel 1: kgen (MFMA).  Kb[p][i][o] = bf16(exp(10 * x[n,i,:].w[m,o,:]))
// (unchanged)
// ---------------------------------------------------------------------------
__global__ __launch_bounds__(256) void kgen(const float* __restrict__ x,
                                            const float* __restrict__ w,
                                            __hip_bfloat16* __restrict__ Kb)
{
    const int pair = blockIdx.y;
    const int n = pair >> 1, m = pair & 1;
    const int r0 = blockIdx.x * 128;
    const int tid = threadIdx.x;
    const int wv  = tid >> 6;
    const int l   = tid & 63;

    __shared__ char xs[128*256];
    __shared__ char ws[128*256];

    {
        const float* xb = x + ((size_t)n*IN_SIZE + r0)*IN_DIM;
        for (int t = tid; t < 4096; t += 256) {
            int row = t >> 5, c4 = t & 31;
            float4 v4 = *(const float4*)&xb[(size_t)row*IN_DIM + c4*4];
            u32 p0 = (u32)f2bf(v4.x) | ((u32)f2bf(v4.y) << 16);
            u32 p1 = (u32)f2bf(v4.z) | ((u32)f2bf(v4.w) << 16);
            int byte = (row*256 + c4*8) ^ ((row & 7) << 4);
            *(u32*)(xs + byte)     = p0;
            *(u32*)(xs + byte + 4) = p1;
        }
    }
    {
        const float* wb = w + (size_t)m*OUT_SIZE*IN_DIM;
        for (int t = tid; t < 4096; t += 256) {
            int row = t >> 5, c4 = t & 31;
            float4 v4 = *(const float4*)&wb[(size_t)row*IN_DIM + c4*4];
            u32 p0 = (u32)f2bf(v4.x) | ((u32)f2bf(v4.y) << 16);
            u32 p1 = (u32)f2bf(v4.z) | ((u32)f2bf(v4.w) << 16);
            int byte = (row*256 + c4*8) ^ ((row & 7) << 4);
            *(u32*)(ws + byte)     = p0;
            *(u32*)(ws + byte + 4) = p1;
        }
    }
    __syncthreads();

    f32x4 acc[2][8];
    #pragma unroll
    for (int ai=0;ai<2;++ai)
        #pragma unroll
        for (int bj=0;bj<8;++bj) acc[ai][bj] = (f32x4){0.f,0.f,0.f,0.f};

    const int lr = l & 15;
    const int lk = (l >> 4) * 16;

    #pragma unroll
    for (int kk = 0; kk < 4; ++kk) {
        bf16x8 a[2];
        #pragma unroll
        for (int ai=0;ai<2;++ai) {
            int row = wv*32 + ai*16 + lr;
            int byte = (row*256 + kk*64 + lk) ^ ((row & 7) << 4);
            a[ai] = *(const bf16x8*)(xs + byte);
        }
        #pragma unroll
        for (int bj=0;bj<8;++bj) {
            int row = bj*16 + lr;
            int byte = (row*256 + kk*64 + lk) ^ ((row & 7) << 4);
            bf16x8 b = *(const bf16x8*)(ws + byte);
            acc[0][bj] = __builtin_amdgcn_mfma_f32_16x16x32_bf16(a[0], b, acc[0][bj], 0, 0, 0);
            acc[1][bj] = __builtin_amdgcn_mfma_f32_16x16x32_bf16(a[1], b, acc[1][bj], 0, 0, 0);
        }
    }

    __hip_bfloat16* out = Kb + (size_t)pair*IN_SIZE*OUT_SIZE + (size_t)r0*OUT_SIZE;
    #pragma unroll
    for (int ai=0;ai<2;++ai) {
        #pragma unroll
        for (int bj=0;bj<8;++bj) {
            #pragma unroll
            for (int j=0;j<4;++j) {
                int i = wv*32 + ai*16 + (l>>4)*4 + j;
                int o = bj*16 + lr;
                float e = __expf(INV_EPS * acc[ai][bj][j]);
                out[(size_t)i*OUT_SIZE + o] = __float2bfloat16(e);
            }
        }
    }
}

// ---------------------------------------------------------------------------
// Kernel 2: sinkhorn. 256 blocks x 512 thr (8 waves, 2/SIMD), half-pair per
// block, 1 block/CU. K is FULLY on-chip: per wave 256 rows = 64 quads ->
// 46 quads in VGPRs (184 regs) + 18 quads in LDS (147.5 KB self-slots),
// 0 streamed. amdgpu_waves_per_eu(2,2) -> 256-VGPR budget (round 5/7 showed
// __launch_bounds__ 2nd arg cannot LOWER the allocator's occupancy target
// for 1024-thr blocks; shrinking the block + pinning waves/EU raises the cap).
// Exchange: fence-free sign-sentinel slots (proven round 4).
// ---------------------------------------------------------------------------
#define PROC_QUAD(cc, qidx)                                                   \
    {                                                                         \
        float k0=bflo((cc).x), k1=bfhi((cc).x), k2=bflo((cc).y), k3=bfhi((cc).y); \
        float k4=bflo((cc).z), k5=bfhi((cc).z), k6=bflo((cc).w), k7=bfhi((cc).w); \
        float p = k0*v[0];                                                    \
        p = fmaf(k1,v[1],p); p = fmaf(k2,v[2],p); p = fmaf(k3,v[3],p);        \
        p = fmaf(k4,v[4],p); p = fmaf(k5,v[5],p); p = fmaf(k6,v[6],p);        \
        p = fmaf(k7,v[7],p);                                                  \
        p = dpp_add<0xB1>(p);                                                 \
        p = dpp_add<0x4E>(p);                                                 \
        p = dpp_add<0x141>(p);                                                \
        p = dpp_add<0x140>(p);                                                \
        float ui = A_MARG * __builtin_amdgcn_rcpf(p);                         \
        acc[0]=fmaf(ui,k0,acc[0]); acc[1]=fmaf(ui,k1,acc[1]);                 \
        acc[2]=fmaf(ui,k2,acc[2]); acc[3]=fmaf(ui,k3,acc[3]);                 \
        acc[4]=fmaf(ui,k4,acc[4]); acc[5]=fmaf(ui,k5,acc[5]);                 \
        acc[6]=fmaf(ui,k6,acc[6]); acc[7]=fmaf(ui,k7,acc[7]);                 \
        if (last && s == 0) uo[uob + (qidx)*4 + grp] = ui;                    \
    }

#define NREG 46
#define NLDS 18

__global__ __attribute__((amdgpu_flat_work_group_size(512, 512), amdgpu_waves_per_eu(2, 2)))
void sinkhorn(const __hip_bfloat16* __restrict__ Kb,
              float* __restrict__ uo,
              float* __restrict__ vo,
              int* __restrict__ slots)
{
    const int bid  = blockIdx.x;
    const int pair = bid >> 1, half = bid & 1;
    const int tid  = threadIdx.x;
    const int wave = tid >> 6;      // 8 waves, 256 rows each
    const int lane = tid & 63;
    const int grp  = lane >> 4;     // row within quad
    const int s    = lane & 15;     // column slice 8s..8s+7

    __shared__ int4  klds[8*NLDS*64];   // 147456 B self-slots
    __shared__ float red[8][128];       //   4096 B
    __shared__ float vnew[128];         //    512 B

    const int4* gp = (const int4*)(Kb)
                   + ((size_t)pair*4096 + half*2048 + wave*256)*16
                   + grp*16 + s;
    const size_t uob = (size_t)pair*IN_SIZE + half*2048 + wave*256;

    // ---- one-time load: 46 quads -> registers, 18 quads -> LDS ----
    int4 kq0  = gp[ 0*64], kq1  = gp[ 1*64], kq2  = gp[ 2*64], kq3  = gp[ 3*64];
    int4 kq4  = gp[ 4*64], kq5  = gp[ 5*64], kq6  = gp[ 6*64], kq7  = gp[ 7*64];
    int4 kq8  = gp[ 8*64], kq9  = gp[ 9*64], kq10 = gp[10*64], kq11 = gp[11*64];
    int4 kq12 = gp[12*64], kq13 = gp[13*64], kq14 = gp[14*64], kq15 = gp[15*64];
    int4 kq16 = gp[16*64], kq17 = gp[17*64], kq18 = gp[18*64], kq19 = gp[19*64];
    int4 kq20 = gp[20*64], kq21 = gp[21*64], kq22 = gp[22*64], kq23 = gp[23*64];
    int4 kq24 = gp[24*64], kq25 = gp[25*64], kq26 = gp[26*64], kq27 = gp[27*64];
    int4 kq28 = gp[28*64], kq29 = gp[29*64], kq30 = gp[30*64], kq31 = gp[31*64];
    int4 kq32 = gp[32*64], kq33 = gp[33*64], kq34 = gp[34*64], kq35 = gp[35*64];
    int4 kq36 = gp[36*64], kq37 = gp[37*64], kq38 = gp[38*64], kq39 = gp[39*64];
    int4 kq40 = gp[40*64], kq41 = gp[41*64], kq42 = gp[42*64], kq43 = gp[43*64];
    int4 kq44 = gp[44*64], kq45 = gp[45*64];
    #pragma unroll
    for (int q = 0; q < NLDS; ++q)
        klds[(wave*NLDS + q)*64 + lane] = gp[(NREG+q)*64];

    float v[8];
    #pragma unroll
    for (int j=0;j<8;++j) v[j] = 1.f;

    for (int it = 0; it < MAX_ITER; ++it) {
        const bool last = (it == MAX_ITER-1);
        float acc[8];
        #pragma unroll
        for (int j=0;j<8;++j) acc[j] = 0.f;

        // ---- register-resident quads (0..45) ----
        PROC_QUAD(kq0,  0)  PROC_QUAD(kq1,  1)  PROC_QUAD(kq2,  2)  PROC_QUAD(kq3,  3)
        PROC_QUAD(kq4,  4)  PROC_QUAD(kq5,  5)  PROC_QUAD(kq6,  6)  PROC_QUAD(kq7,  7)
        PROC_QUAD(kq8,  8)  PROC_QUAD(kq9,  9)  PROC_QUAD(kq10,10)  PROC_QUAD(kq11,11)
        PROC_QUAD(kq12,12)  PROC_QUAD(kq13,13)  PROC_QUAD(kq14,14)  PROC_QUAD(kq15,15)
        PROC_QUAD(kq16,16)  PROC_QUAD(kq17,17)  PROC_QUAD(kq18,18)  PROC_QUAD(kq19,19)
        PROC_QUAD(kq20,20)  PROC_QUAD(kq21,21)  PROC_QUAD(kq22,22)  PROC_QUAD(kq23,23)
        PROC_QUAD(kq24,24)  PROC_QUAD(kq25,25)  PROC_QUAD(kq26,26)  PROC_QUAD(kq27,27)
        PROC_QUAD(kq28,28)  PROC_QUAD(kq29,29)  PROC_QUAD(kq30,30)  PROC_QUAD(kq31,31)
        PROC_QUAD(kq32,32)  PROC_QUAD(kq33,33)  PROC_QUAD(kq34,34)  PROC_QUAD(kq35,35)
        PROC_QUAD(kq36,36)  PROC_QUAD(kq37,37)  PROC_QUAD(kq38,38)  PROC_QUAD(kq39,39)
        PROC_QUAD(kq40,40)  PROC_QUAD(kq41,41)  PROC_QUAD(kq42,42)  PROC_QUAD(kq43,43)
        PROC_QUAD(kq44,44)  PROC_QUAD(kq45,45)

        // ---- LDS-resident quads (46..63; self-slot reads, no barrier) ----
        #pragma unroll
        for (int q = 0; q < NLDS; ++q) {
            int4 cc = klds[(wave*NLDS + q)*64 + lane];
            PROC_QUAD(cc, NREG+q)
        }

        // ---- column-sum reduce + cross-block exchange ----
        #pragma unroll
        for (int j=0;j<8;++j) {
            acc[j] += __shfl_xor(acc[j], 16, 64);
            acc[j] += __shfl_xor(acc[j], 32, 64);
        }
        if (lane < 16) {
            *(float4*)&red[wave][8*s]   = make_float4(acc[0],acc[1],acc[2],acc[3]);
            *(float4*)&red[wave][8*s+4] = make_float4(acc[4],acc[5],acc[6],acc[7]);
        }
        __syncthreads();
        if (tid < 128) {
            float own = 0.f;
            #pragma unroll
            for (int w_ = 0; w_ < 8; ++w_) own += red[w_][tid];
            int* myslot = slots + ((size_t)it*NBLK + bid)*128;
            int* otslot = slots + ((size_t)it*NBLK + (bid^1))*128;
            __hip_atomic_store(&myslot[tid], __float_as_int(-own),
                               __ATOMIC_RELAXED, __HIP_MEMORY_SCOPE_AGENT);
            int wrd;
            do {
                wrd = __hip_atomic_load(&otslot[tid], __ATOMIC_RELAXED,
                                        __HIP_MEMORY_SCOPE_AGENT);
            } while (wrd >= 0);
            float other = -__int_as_float(wrd);
            float vv = __builtin_amdgcn_rcpf(own + other);
            vnew[tid] = vv;
            if (last && half == 0) vo[(size_t)pair*OUT_SIZE + tid] = vv;
        }
        __syncthreads();
        float4 va = *(const float4*)&vnew[8*s];
        float4 vb = *(const float4*)&vnew[8*s+4];
        v[0]=va.x; v[1]=va.y; v[2]=va.z; v[3]=va.w;
        v[4]=vb.x; v[5]=vb.y; v[6]=vb.z; v[7]=vb.w;
    }
}

// ---------------------------------------------------------------------------
// Kernel 3: outgemm (MFMA).  (unchanged)
// ---------------------------------------------------------------------------
__global__ __launch_bounds__(256) void outgemm(const __hip_bfloat16* __restrict__ Kb,
                                               const float* __restrict__ uo,
                                               const float* __restrict__ vo,
                                               const float* __restrict__ x,
                                               float* __restrict__ out)
{
    const int dh = blockIdx.x;
    const int pair = blockIdx.y;
    const int n = pair >> 1, m = pair & 1;
    const int tid = threadIdx.x;
    const int wv  = tid >> 6;
    const int l   = tid & 63;

    __shared__ u32  ka[64][66];
    __shared__ float ua[64];
    __shared__ float xa[64][68];
    __shared__ char At[128*128];
    __shared__ char Bt[64*128];

    f32x4 acc[2][4];
    #pragma unroll
    for (int ai=0;ai<2;++ai)
        #pragma unroll
        for (int bj=0;bj<4;++bj) acc[ai][bj] = (f32x4){0.f,0.f,0.f,0.f};

    const int lr = l & 15;
    const int lk = (l >> 4) * 16;

    for (int chunk = 0; chunk < 64; ++chunk) {
        const int i0 = chunk * 64;
        {
            const u32* ksrc = (const u32*)(Kb + ((size_t)pair*IN_SIZE + i0)*OUT_SIZE);
            for (int t = tid; t < 4096; t += 256) ka[t>>6][t&63] = ksrc[t];
            if (tid < 64) ua[tid] = uo[(size_t)pair*IN_SIZE + i0 + tid];
            const float* xsrc = x + ((size_t)n*IN_SIZE + i0)*IN_DIM + dh*64;
            for (int t = tid; t < 1024; t += 256) {
                int i = t >> 4, c4 = t & 15;
                *(float4*)&xa[i][c4*4] = *(const float4*)&xsrc[(size_t)i*IN_DIM + c4*4];
            }
        }
        __syncthreads();
        {
            int o = tid >> 1, seg = tid & 1;
            unsigned short us[32];
            #pragma unroll
            for (int k=0;k<32;++k) {
                int i = seg*32 + k;
                u32 kk = ka[i][o>>1];
                float f = (o&1) ? bfhi(kk) : bflo(kk);
                us[k] = f2bf(f * ua[i]);
            }
            #pragma unroll
            for (int q=0;q<4;++q) {
                int4 wbuf;
                u32* wp = (u32*)&wbuf;
                #pragma unroll
                for (int e=0;e<4;++e)
                    wp[e] = (u32)us[q*8 + 2*e] | ((u32)us[q*8 + 2*e + 1] << 16);
                int byte = (o*128 + seg*64 + q*16) ^ ((o & 7) << 4);
                *(int4*)(At + byte) = wbuf;
            }
        }
        {
            int d = tid >> 2, s2 = tid & 3;
            unsigned short us[16];
            #pragma unroll
            for (int k=0;k<16;++k) us[k] = f2bf(xa[s2*16 + k][d]);
            #pragma unroll
            for (int q=0;q<2;++q) {
                int4 wbuf;
                u32* wp = (u32*)&wbuf;
                #pragma unroll
                for (int e=0;e<4;++e)
                    wp[e] = (u32)us[q*8 + 2*e] | ((u32)us[q*8 + 2*e + 1] << 16);
                int byte = (d*128 + s2*32 + q*16) ^ ((d & 7) << 4);
                *(int4*)(Bt + byte) = wbuf;
            }
        }
        __syncthreads();
        #pragma unroll
        for (int kk = 0; kk < 2; ++kk) {
            bf16x8 a[2];
            #pragma unroll
            for (int ai=0;ai<2;++ai) {
                int row = wv*32 + ai*16 + lr;
                int byte = (row*128 + kk*64 + lk) ^ ((row & 7) << 4);
                a[ai] = *(const bf16x8*)(At + byte);
            }
            #pragma unroll
            for (int bj=0;bj<4;++bj) {
                int row = bj*16 + lr;
                int byte = (row*128 + kk*64 + lk) ^ ((row & 7) << 4);
                bf16x8 b = *(const bf16x8*)(Bt + byte);
                acc[0][bj] = __builtin_amdgcn_mfma_f32_16x16x32_bf16(a[0], b, acc[0][bj], 0, 0, 0);
                acc[1][bj] = __builtin_amdgcn_mfma_f32_16x16x32_bf16(a[1], b, acc[1][bj], 0, 0, 0);
            }
        }
        __syncthreads();
    }

    #pragma unroll
    for (int ai=0;ai<2;++ai) {
        #pragma unroll
        for (int bj=0;bj<4;++bj) {
            #pragma unroll
            for (int j=0;j<4;++j) {
                int o = wv*32 + ai*16 + (l>>4)*4 + j;
                int d = dh*64 + bj*16 + lr;
                float vv = vo[(size_t)pair*OUT_SIZE + o];
                out[(((size_t)n*OUT_SIZE + o)*HEADS + m)*IN_DIM + d] = acc[ai][bj][j] * vv;
            }
        }
    }
}

// ---------------------------------------------------------------------------
extern "C" void kernel_launch(void* const* d_in, const int* in_sizes, int n_in,
                              void* d_out, int out_size, void* d_ws, size_t ws_size,
                              hipStream_t stream)
{
    const float* x = (const float*)d_in[0];
    const float* w = (const float*)d_in[1];
    float* out = (float*)d_out;

    char* ws = (char*)d_ws;
    __hip_bfloat16* Kb = (__hip_bfloat16*)ws;                 // 134,217,728 B
    float* uo  = (float*)(ws + 134217728);                    //   2,097,152 B
    float* vo  = (float*)(ws + 134217728 + 2097152);          //      65,536 B
    int* slots = (int*)(ws + 134217728 + 2097152 + 65536);    //   6,553,600 B

    // slots MUST be zeroed (0xAA poison has sign bit set -> false sentinel)
    hipMemsetAsync(slots, 0, (size_t)MAX_ITER*NBLK*128*sizeof(int), stream);

    kgen    <<<dim3(IN_SIZE/128, NPAIR), 256,  0, stream>>>(x, w, Kb);
    sinkhorn<<<dim3(NBLK),               512,  0, stream>>>(Kb, uo, vo, slots);
    outgemm <<<dim3(2, NPAIR),           256,  0, stream>>>(Kb, uo, vo, x, out);
}